// Round 3
// baseline (50.387 us; speedup 1.0000x reference)
//
#include <hip/hip_runtime.h>

// SymmetricChannel: B=128, L=64, V=4096, P=0.1  — fully fused single kernel.
//   mask       = rand_mask < P                    (B*L = 8192 rows)
//   any_hit    = mask.any()
//   col_hit[v] = OR over masked positions of (replacement_ids == v)
//   row masked:   out[v] = col_hit[v] ? 1-eos : (v==0 ? eos : 0),  eos = probs[row][0]
//   row unmasked: out[v] = probs[row][v]
//   entropy_out = entropy + (any_hit ? H2(P)+log2(L-2) : 0)
//
// Fusion trick: each masked block (~10% of rows) rebuilds the 4096-bit
// col_hit bitmask itself from rand_mask+repl (64 KB, L2-resident broadcast),
// removing the serial single-block prefix kernel + launch gap.

#define V_DIM   4096
#define N_ROWS  8192          // B*L
#define P_CONST 0.1f
// H2(0.1) + log2(62), double-precision constant
#define DELTA_CONST 6.4231919039761563f

typedef float f32x4 __attribute__((ext_vector_type(4)));

__global__ __launch_bounds__(256)
void sc_fused_kernel(const f32x4* __restrict__ probs4,
                     const float* __restrict__ probs_s,
                     const f32x4* __restrict__ rand4,
                     const float* __restrict__ rand_s,
                     const int*   __restrict__ repl,
                     const float* __restrict__ entropy,
                     f32x4*       __restrict__ out4,
                     float*       __restrict__ entropy_out)
{
    __shared__ unsigned colhit[V_DIM / 32];
    __shared__ unsigned anyflag;
    const int t   = threadIdx.x;
    const int bid = blockIdx.x;

    if (bid < N_ROWS) {
        const int  row      = bid;
        const long rowbase4 = (long)row * (V_DIM / 4);
        const bool m        = rand_s[row] < P_CONST;   // block-uniform

        if (m) {
            // ---- rebuild col_hit bitmask in LDS (reads are L2-hits) ----
            if (t < V_DIM / 32) colhit[t] = 0u;
            __syncthreads();
            #pragma unroll
            for (int k = 0; k < N_ROWS / 4 / 256; ++k) {   // 8 iters
                const int   i4 = t + k * 256;
                const f32x4 r  = rand4[i4];
                const int   i0 = i4 * 4;
                if (r.x < P_CONST) { const int id = repl[i0    ]; atomicOr(&colhit[id >> 5], 1u << (id & 31)); }
                if (r.y < P_CONST) { const int id = repl[i0 + 1]; atomicOr(&colhit[id >> 5], 1u << (id & 31)); }
                if (r.z < P_CONST) { const int id = repl[i0 + 2]; atomicOr(&colhit[id >> 5], 1u << (id & 31)); }
                if (r.w < P_CONST) { const int id = repl[i0 + 3]; atomicOr(&colhit[id >> 5], 1u << (id & 31)); }
            }
            __syncthreads();

            // ---- synthesize the row (no probs-row read except eos) ----
            const float eos = probs_s[(long)row * V_DIM];
            const float om  = 1.0f - eos;
            #pragma unroll
            for (int k = 0; k < 4; ++k) {
                const int      c4 = t + k * 256;     // float4 index in row
                const unsigned w  = colhit[c4 >> 3];
                const int      c0 = c4 * 4;
                f32x4 r;
                r.x = ((w >> ( c0      & 31)) & 1u) ? om : ((c0 == 0) ? eos : 0.0f);
                r.y = ((w >> ((c0 + 1) & 31)) & 1u) ? om : 0.0f;
                r.z = ((w >> ((c0 + 2) & 31)) & 1u) ? om : 0.0f;
                r.w = ((w >> ((c0 + 3) & 31)) & 1u) ? om : 0.0f;
                __builtin_nontemporal_store(r, &out4[rowbase4 + c4]);
            }
        } else {
            // ---- straight streaming copy ----
            #pragma unroll
            for (int k = 0; k < 4; ++k) {
                const int   c4 = t + k * 256;
                const f32x4 v  = __builtin_nontemporal_load(&probs4[rowbase4 + c4]);
                __builtin_nontemporal_store(v, &out4[rowbase4 + c4]);
            }
        }
    } else {
        // ---- entropy blocks: 32 blocks x 256 threads = 8192 elements ----
        const int eb = bid - N_ROWS;
        if (t == 0) anyflag = 0u;
        __syncthreads();
        bool la = false;
        #pragma unroll
        for (int k = 0; k < N_ROWS / 4 / 256; ++k) {
            const f32x4 r = rand4[t + k * 256];
            la = la || (r.x < P_CONST) || (r.y < P_CONST) ||
                       (r.z < P_CONST) || (r.w < P_CONST);
        }
        if (la) atomicOr(&anyflag, 1u);
        __syncthreads();
        const float d = anyflag ? DELTA_CONST : 0.0f;
        const int   i = eb * 256 + t;
        entropy_out[i] = entropy[i] + d;
    }
}

extern "C" void kernel_launch(void* const* d_in, const int* in_sizes, int n_in,
                              void* d_out, int out_size, void* d_ws, size_t ws_size,
                              hipStream_t stream)
{
    const float* probs     = (const float*)d_in[0];
    const float* entropy   = (const float*)d_in[1];
    const float* rand_mask = (const float*)d_in[2];
    const int*   repl      = (const int*)  d_in[3];

    float* out         = (float*)d_out;
    float* probs_out   = out;                          // B*L*V floats
    float* entropy_out = out + (long)N_ROWS * V_DIM;   // B*L floats

    sc_fused_kernel<<<N_ROWS + 32, 256, 0, stream>>>(
        (const f32x4*)probs, probs,
        (const f32x4*)rand_mask, rand_mask,
        repl, entropy,
        (f32x4*)probs_out, entropy_out);
}

// Round 4
// 47.547 us; speedup vs baseline: 1.0597x; 1.0597x over previous
//
#include <hip/hip_runtime.h>

// SymmetricChannel: B=128, L=64, V=4096, P=0.1 — split: tiny vectorized prefix
// (colhit bitmask + any_hit + entropy_out) + 2-rows-per-block streaming main.

#define V_DIM   4096
#define V4      (V_DIM / 4)      // 1024 f32x4 per row
#define N_ROWS  8192             // B*L
#define P_CONST 0.1f
// H2(0.1) + log2(62), double-precision constant
#define DELTA_CONST 6.4231919039761563f

typedef float f32x4 __attribute__((ext_vector_type(4)));

// ---------------- kernel 1: colhit + any_hit + entropy_out ------------------
__global__ __launch_bounds__(1024)
void sc_prefix_kernel(const f32x4* __restrict__ rand4,
                      const int4*  __restrict__ repl4,
                      const f32x4* __restrict__ entropy4,
                      unsigned*    __restrict__ colhit_out,   // 128 words in d_ws
                      f32x4*       __restrict__ entropy_out4)
{
    __shared__ unsigned colhit[V_DIM / 32];
    __shared__ unsigned anyflag;
    const int t = threadIdx.x;
    if (t < V_DIM / 32) colhit[t] = 0u;
    if (t == 0) anyflag = 0u;
    __syncthreads();

    // Load ALL rand + repl up front (independent loads, no dependency chain)
    const f32x4 r0 = rand4[t], r1 = rand4[t + 1024];
    const int4  q0 = repl4[t], q1 = repl4[t + 1024];

    bool any = false;
    {
        if (r0.x < P_CONST) { any = true; atomicOr(&colhit[q0.x >> 5], 1u << (q0.x & 31)); }
        if (r0.y < P_CONST) { any = true; atomicOr(&colhit[q0.y >> 5], 1u << (q0.y & 31)); }
        if (r0.z < P_CONST) { any = true; atomicOr(&colhit[q0.z >> 5], 1u << (q0.z & 31)); }
        if (r0.w < P_CONST) { any = true; atomicOr(&colhit[q0.w >> 5], 1u << (q0.w & 31)); }
        if (r1.x < P_CONST) { any = true; atomicOr(&colhit[q1.x >> 5], 1u << (q1.x & 31)); }
        if (r1.y < P_CONST) { any = true; atomicOr(&colhit[q1.y >> 5], 1u << (q1.y & 31)); }
        if (r1.z < P_CONST) { any = true; atomicOr(&colhit[q1.z >> 5], 1u << (q1.z & 31)); }
        if (r1.w < P_CONST) { any = true; atomicOr(&colhit[q1.w >> 5], 1u << (q1.w & 31)); }
    }
    if (any) atomicOr(&anyflag, 1u);
    __syncthreads();

    if (t < V_DIM / 32) colhit_out[t] = colhit[t];

    const float d = anyflag ? DELTA_CONST : 0.0f;
    f32x4 e0 = entropy4[t], e1 = entropy4[t + 1024];
    e0.x += d; e0.y += d; e0.z += d; e0.w += d;
    e1.x += d; e1.y += d; e1.z += d; e1.w += d;
    entropy_out4[t]        = e0;
    entropy_out4[t + 1024] = e1;
}

// ---------------- helper: synthesize one masked row -------------------------
__device__ __forceinline__ void synth_row(const unsigned* colhit, float eos,
                                          long rowbase4, int t,
                                          f32x4* __restrict__ out4)
{
    const float om = 1.0f - eos;
    #pragma unroll
    for (int k = 0; k < 4; ++k) {
        const int      c4 = t + k * 256;
        const unsigned w  = colhit[c4 >> 3];
        const int      c0 = c4 * 4;
        f32x4 r;
        r.x = ((w >> ( c0      & 31)) & 1u) ? om : ((c0 == 0) ? eos : 0.0f);
        r.y = ((w >> ((c0 + 1) & 31)) & 1u) ? om : 0.0f;
        r.z = ((w >> ((c0 + 2) & 31)) & 1u) ? om : 0.0f;
        r.w = ((w >> ((c0 + 3) & 31)) & 1u) ? om : 0.0f;
        __builtin_nontemporal_store(r, &out4[rowbase4 + c4]);
    }
}

// ---------------- kernel 2: probs rewrite, 2 rows per block ------------------
__global__ __launch_bounds__(256)
void sc_main_kernel(const f32x4*    __restrict__ probs4,
                    const float*    __restrict__ probs_s,
                    const float*    __restrict__ rand_s,
                    const unsigned* __restrict__ colhit_g,
                    f32x4*          __restrict__ out4)
{
    __shared__ unsigned colhit[V_DIM / 32];
    const int  t     = threadIdx.x;
    const int  row0  = blockIdx.x * 2;
    const bool m0    = rand_s[row0]     < P_CONST;
    const bool m1    = rand_s[row0 + 1] < P_CONST;
    const long base4 = (long)row0 * V4;

    if (!m0 && !m1) {
        // fast path: contiguous 32 KB chunk, 8 loads in flight per thread
        #pragma unroll
        for (int k = 0; k < 8; ++k) {
            const f32x4 v = probs4[base4 + t + k * 256];
            __builtin_nontemporal_store(v, &out4[base4 + t + k * 256]);
        }
        return;
    }

    // at least one masked row: pull colhit bitmask (512 B, L2-resident)
    if (t < V_DIM / 32) colhit[t] = colhit_g[t];
    __syncthreads();

    if (m0) {
        synth_row(colhit, probs_s[(long)row0 * V_DIM], base4, t, out4);
    } else {
        #pragma unroll
        for (int k = 0; k < 4; ++k) {
            const f32x4 v = probs4[base4 + t + k * 256];
            __builtin_nontemporal_store(v, &out4[base4 + t + k * 256]);
        }
    }
    if (m1) {
        synth_row(colhit, probs_s[(long)(row0 + 1) * V_DIM], base4 + V4, t, out4);
    } else {
        #pragma unroll
        for (int k = 0; k < 4; ++k) {
            const f32x4 v = probs4[base4 + V4 + t + k * 256];
            __builtin_nontemporal_store(v, &out4[base4 + V4 + t + k * 256]);
        }
    }
}

extern "C" void kernel_launch(void* const* d_in, const int* in_sizes, int n_in,
                              void* d_out, int out_size, void* d_ws, size_t ws_size,
                              hipStream_t stream)
{
    const float* probs     = (const float*)d_in[0];
    const float* entropy   = (const float*)d_in[1];
    const float* rand_mask = (const float*)d_in[2];
    const int*   repl      = (const int*)  d_in[3];

    float*    out         = (float*)d_out;
    float*    probs_out   = out;                          // B*L*V floats
    float*    entropy_out = out + (long)N_ROWS * V_DIM;   // B*L floats
    unsigned* colhit_ws   = (unsigned*)d_ws;              // 128 words

    sc_prefix_kernel<<<1, 1024, 0, stream>>>(
        (const f32x4*)rand_mask, (const int4*)repl,
        (const f32x4*)entropy, colhit_ws, (f32x4*)entropy_out);

    sc_main_kernel<<<N_ROWS / 2, 256, 0, stream>>>(
        (const f32x4*)probs, probs, rand_mask, colhit_ws, (f32x4*)probs_out);
}

// Round 5
// 42.707 us; speedup vs baseline: 1.1798x; 1.1133x over previous
//
#include <hip/hip_runtime.h>

// SymmetricChannel: B=128, L=64, V=4096, P=0.1 — single kernel, zero
// cross-block dependency.
//   blocks [0,256):    "writer" blocks — each redundantly rebuilds the
//                      4096-bit col_hit mask from rand+repl (96 KB,
//                      L2-broadcast), synthesizes masked rows in its own
//                      32-row slice, and writes its entropy slice.
//   blocks [256,4352): "copy" blocks — each streams 2 unmasked rows
//                      (32 KB), skipping masked rows entirely.

#define V_DIM   4096
#define V4      (V_DIM / 4)          // 1024 f32x4 per row
#define N_ROWS  8192                 // B*L
#define NWRITER 256
#define WROWS   (N_ROWS / NWRITER)   // 32 rows per writer block
#define P_CONST 0.1f
// H2(0.1) + log2(62), double-precision constant
#define DELTA_CONST 6.4231919039761563f

typedef float f32x4 __attribute__((ext_vector_type(4)));

__device__ __forceinline__ void synth_row(const unsigned* colhit, float eos,
                                          long rowbase4, int t,
                                          f32x4* __restrict__ out4)
{
    const float om = 1.0f - eos;
    #pragma unroll
    for (int k = 0; k < 4; ++k) {
        const int      c4 = t + k * 256;
        const unsigned w  = colhit[c4 >> 3];
        const int      c0 = c4 * 4;
        f32x4 r;
        r.x = ((w >> ( c0      & 31)) & 1u) ? om : ((c0 == 0) ? eos : 0.0f);
        r.y = ((w >> ((c0 + 1) & 31)) & 1u) ? om : 0.0f;
        r.z = ((w >> ((c0 + 2) & 31)) & 1u) ? om : 0.0f;
        r.w = ((w >> ((c0 + 3) & 31)) & 1u) ? om : 0.0f;
        __builtin_nontemporal_store(r, &out4[rowbase4 + c4]);
    }
}

__global__ __launch_bounds__(256)
void sc_onekernel(const f32x4* __restrict__ probs4,
                  const float* __restrict__ probs_s,
                  const f32x4* __restrict__ rand4,
                  const float* __restrict__ rand_s,
                  const int4*  __restrict__ repl4,
                  const float* __restrict__ entropy,
                  f32x4*       __restrict__ out4,
                  float*       __restrict__ entropy_out)
{
    const int t   = threadIdx.x;
    const int bid = blockIdx.x;

    if (bid < NWRITER) {
        // ---------------- writer block ----------------
        __shared__ unsigned colhit[V_DIM / 32];
        __shared__ unsigned anyflag;
        if (t < V_DIM / 32) colhit[t] = 0u;
        if (t == 0) anyflag = 0u;
        __syncthreads();

        bool any = false;
        #pragma unroll
        for (int k = 0; k < N_ROWS / 4 / 256; ++k) {     // 8 iters
            const int   i4 = t + k * 256;
            const f32x4 r  = rand4[i4];
            const int4  q  = repl4[i4];
            if (r.x < P_CONST) { any = true; atomicOr(&colhit[q.x >> 5], 1u << (q.x & 31)); }
            if (r.y < P_CONST) { any = true; atomicOr(&colhit[q.y >> 5], 1u << (q.y & 31)); }
            if (r.z < P_CONST) { any = true; atomicOr(&colhit[q.z >> 5], 1u << (q.z & 31)); }
            if (r.w < P_CONST) { any = true; atomicOr(&colhit[q.w >> 5], 1u << (q.w & 31)); }
        }
        if (any) atomicOr(&anyflag, 1u);
        __syncthreads();

        // entropy slice (32 elems)
        const float d  = anyflag ? DELTA_CONST : 0.0f;
        const int   e0 = bid * WROWS;
        if (t < WROWS) entropy_out[e0 + t] = entropy[e0 + t] + d;

        // synthesize masked rows in this block's 32-row slice
        for (int r = e0; r < e0 + WROWS; ++r) {
            if (rand_s[r] < P_CONST) {                    // uniform branch
                synth_row(colhit, probs_s[(long)r * V_DIM],
                          (long)r * V4, t, out4);
            }
        }
    } else {
        // ---------------- copy block: 2 rows ----------------
        const int  r0    = (bid - NWRITER) * 2;
        const bool m0    = rand_s[r0]     < P_CONST;
        const bool m1    = rand_s[r0 + 1] < P_CONST;
        const long base4 = (long)r0 * V4;

        if (!m0 && !m1) {
            // fast path: contiguous 32 KB, 8 loads in flight
            #pragma unroll
            for (int k = 0; k < 8; ++k) {
                const f32x4 v = probs4[base4 + t + k * 256];
                __builtin_nontemporal_store(v, &out4[base4 + t + k * 256]);
            }
            return;
        }
        if (!m0) {
            #pragma unroll
            for (int k = 0; k < 4; ++k) {
                const f32x4 v = probs4[base4 + t + k * 256];
                __builtin_nontemporal_store(v, &out4[base4 + t + k * 256]);
            }
        }
        if (!m1) {
            #pragma unroll
            for (int k = 0; k < 4; ++k) {
                const f32x4 v = probs4[base4 + V4 + t + k * 256];
                __builtin_nontemporal_store(v, &out4[base4 + V4 + t + k * 256]);
            }
        }
    }
}

extern "C" void kernel_launch(void* const* d_in, const int* in_sizes, int n_in,
                              void* d_out, int out_size, void* d_ws, size_t ws_size,
                              hipStream_t stream)
{
    const float* probs     = (const float*)d_in[0];
    const float* entropy   = (const float*)d_in[1];
    const float* rand_mask = (const float*)d_in[2];
    const int*   repl      = (const int*)  d_in[3];

    float* out         = (float*)d_out;
    float* probs_out   = out;                          // B*L*V floats
    float* entropy_out = out + (long)N_ROWS * V_DIM;   // B*L floats

    sc_onekernel<<<NWRITER + N_ROWS / 2, 256, 0, stream>>>(
        (const f32x4*)probs, probs,
        (const f32x4*)rand_mask, rand_mask,
        (const int4*)repl, entropy,
        (f32x4*)probs_out, entropy_out);
}